// Round 8
// baseline (133.392 us; speedup 1.0000x reference)
//
#include <hip/hip_runtime.h>

typedef __attribute__((ext_vector_type(8))) short short8;
typedef __attribute__((ext_vector_type(4))) float f32x4;

#define C_DIM 128
#define K_CODES 1024
#define TOT 8388608   // 16*128*64*64
#define NBLK 512      // 128 contiguous pixels per block

__device__ __forceinline__ unsigned int f2bf1(float f) {
  unsigned int u = __float_as_uint(f);
  return (u + 0x7FFFu + ((u >> 16) & 1u)) >> 16;   // RNE fp32->bf16
}
__device__ __forceinline__ unsigned int f2bf2(float lo, float hi) {
  return f2bf1(lo) | (f2bf1(hi) << 16);
}

// ---- P: bf16 codebook (raw + staging-swizzled) + (1+||e||^2) + zero used ----
// Swizzled layout: granule(code r, ks, q) -> (r>>6)*1024 + ((r>>4)&3)*256
//   + ks*64 + (r&15)*4 + q  == the exact LDS image the K-loop consumes, so
// vq_main staging is a pure contiguous copy.
__global__ void prep_kernel(const float* __restrict__ cb,
                            unsigned short* __restrict__ ebf,
                            unsigned short* __restrict__ ebsw,
                            float* __restrict__ nsq1,
                            int* __restrict__ used) {
  int gid = blockIdx.x * 256 + threadIdx.x;     // 512*256 == K*C exactly
  unsigned short b = (unsigned short)f2bf1(cb[gid]);
  ebf[gid] = b;
  int r = gid >> 7, c = gid & 127;
  int ks = c >> 5, q = (c >> 3) & 3, u = c & 7;
  int dstg = (r >> 6) * 1024 + ((r >> 4) & 3) * 256 + ks * 64 + (r & 15) * 4 + q;
  ebsw[dstg * 8 + u] = b;
  if (gid < K_CODES) {
    float s = 0.f;
    #pragma unroll 8
    for (int cc = 0; cc < C_DIM; ++cc) { float v = cb[gid * C_DIM + cc]; s += v * v; }
    nsq1[gid] = 1.0f + s;      // +1 keeps d positive -> u32-monotone float bits
    used[gid] = 0;
  }
}

// ---- M: block = 128 px; wave = 64 px x 512 codes; z read ONCE ----
// R7 post-mortem: residual ~36us = two z passes + staging round-trip + barrier
// tail. This round: z staged once into resident 32KB LDS (bf16(-2z)); A-frags
// AND the epilogue (z = -0.5*val, exact rescale) both read it — kills the
// 33.5MB epilogue global re-read. B-staging is a contiguous copy from the
// pre-swizzled codebook (1KB-coalesced loads issued before consume, lane-linear
// ds_writes after — zero excess bank rounds, explicit latency hiding).
// Math (verified R4-R7): A=bf16(-2z), MFMA C-init = 1+||e||^2 -> d directly;
// key=(bits(d)&~1023)|code, argmin via u32 min. (256,3): no spill (R2 lesson).
__global__ __launch_bounds__(256, 3)
void vq_main(const float* __restrict__ zin,
             const unsigned short* __restrict__ ebf,
             const unsigned short* __restrict__ ebsw,
             const float* __restrict__ nsq1,
             int* __restrict__ used, float* __restrict__ lossp,
             float* __restrict__ out) {
  __shared__ __align__(16) uint4 bG[2][1024];   // 2 x 16KB: 64-code chunks
  __shared__ __align__(16) uint4 zG[2048];      // 32KB: bf16(-2z), resident
  __shared__ float nsq_s[K_CODES];
  __shared__ unsigned int mergeK[128][2];
  __shared__ int   widx[128];
  __shared__ float wsum[4];

  const int t  = threadIdx.x;
  const int L  = t & 63;
  const int wv = t >> 6;        // wave 0..3
  const int ph = wv >> 1;       // pixel half: px [ph*64, ph*64+64)
  const int kh = wv & 1;        // code half: jj tiles {kh*2, kh*2+1}
  const int q  = L >> 4;        // lane quad
  const int nL = L & 15;

  const int bb = blockIdx.x >> 5;          // batch 0..15
  const int hg = blockIdx.x & 31;          // 128-px group
  const int zoff = bb * (C_DIM * 4096) + hg * 128;   // + c*4096 + p

  for (int i = t; i < K_CODES; i += 256) nsq_s[i] = nsq1[i];

  const uint4* __restrict__ esw = (const uint4*)ebsw;  // swizzled granules
  const uint4* __restrict__ ebv = (const uint4*)ebf;   // raw row granules

  // ---- stage chunk 0 (contiguous copy) + z -> zG (256B-coalesced loads)
  #pragma unroll
  for (int p = 0; p < 4; ++p) bG[0][p * 256 + t] = esw[p * 256 + t];
  {
    const int w = t & 127;
    const int pt = w >> 4, mL = w & 15;
    #pragma unroll
    for (int p = 0; p < 8; ++p) {
      const int oct = p * 2 + (t >> 7);    // ks*4+q channel octet
      const int ks = oct >> 2, qq = oct & 3;
      float v[8];
      #pragma unroll
      for (int u = 0; u < 8; ++u)
        v[u] = zin[zoff + (oct * 8 + u) * 4096 + w];
      uint4 val;
      val.x = f2bf2(-2.f * v[0], -2.f * v[1]);
      val.y = f2bf2(-2.f * v[2], -2.f * v[3]);
      val.z = f2bf2(-2.f * v[4], -2.f * v[5]);
      val.w = f2bf2(-2.f * v[6], -2.f * v[7]);
      zG[ks * 512 + pt * 64 + qq * 16 + ((mL + 4 * (pt + qq)) & 15)] = val;
    }
  }
  __syncthreads();

  // ---- A fragments from zG (reused across all chunks)
  short8 afrag[16];
  {
    const short8* zp = (const short8*)zG;
    #pragma unroll
    for (int mt = 0; mt < 4; ++mt) {
      const int pt = ph * 4 + mt;
      #pragma unroll
      for (int ks = 0; ks < 4; ++ks)
        afrag[mt * 4 + ks] = zp[ks * 512 + pt * 64 + q * 16 + ((nL + 4 * (pt + q)) & 15)];
    }
  }

  unsigned int kmin[16];
  #pragma unroll
  for (int i = 0; i < 16; ++i) kmin[i] = 0xFFFFFFFFu;

  // ---- K loop: 16 chunks; loads first, consume, ds_write after, barrier
  #pragma unroll 1
  for (int ch = 0; ch < 16; ++ch) {
    const int cur = ch & 1;
    uint4 st[4];
    if (ch < 15) {
      #pragma unroll
      for (int p = 0; p < 4; ++p) st[p] = esw[(ch + 1) * 1024 + p * 256 + t];
    }
    const short8* bp = (const short8*)bG[cur];
    #pragma unroll
    for (int j2 = 0; j2 < 2; ++j2) {
      const int jj = kh * 2 + j2;
      const int row = ch * 64 + jj * 16 + nL;    // this lane's code
      short8 b0 = bp[jj * 256 + 0 * 64 + nL * 4 + q];
      short8 b1 = bp[jj * 256 + 1 * 64 + nL * 4 + q];
      short8 b2 = bp[jj * 256 + 2 * 64 + nL * 4 + q];
      short8 b3 = bp[jj * 256 + 3 * 64 + nL * 4 + q];
      const float nv = nsq_s[row];
      f32x4 a0 = {nv, nv, nv, nv};
      f32x4 a1 = {nv, nv, nv, nv};
      f32x4 a2 = {nv, nv, nv, nv};
      f32x4 a3 = {nv, nv, nv, nv};
      a0 = __builtin_amdgcn_mfma_f32_16x16x32_bf16(afrag[0],  b0, a0, 0, 0, 0);
      a1 = __builtin_amdgcn_mfma_f32_16x16x32_bf16(afrag[4],  b0, a1, 0, 0, 0);
      a2 = __builtin_amdgcn_mfma_f32_16x16x32_bf16(afrag[8],  b0, a2, 0, 0, 0);
      a3 = __builtin_amdgcn_mfma_f32_16x16x32_bf16(afrag[12], b0, a3, 0, 0, 0);
      a0 = __builtin_amdgcn_mfma_f32_16x16x32_bf16(afrag[1],  b1, a0, 0, 0, 0);
      a1 = __builtin_amdgcn_mfma_f32_16x16x32_bf16(afrag[5],  b1, a1, 0, 0, 0);
      a2 = __builtin_amdgcn_mfma_f32_16x16x32_bf16(afrag[9],  b1, a2, 0, 0, 0);
      a3 = __builtin_amdgcn_mfma_f32_16x16x32_bf16(afrag[13], b1, a3, 0, 0, 0);
      a0 = __builtin_amdgcn_mfma_f32_16x16x32_bf16(afrag[2],  b2, a0, 0, 0, 0);
      a1 = __builtin_amdgcn_mfma_f32_16x16x32_bf16(afrag[6],  b2, a1, 0, 0, 0);
      a2 = __builtin_amdgcn_mfma_f32_16x16x32_bf16(afrag[10], b2, a2, 0, 0, 0);
      a3 = __builtin_amdgcn_mfma_f32_16x16x32_bf16(afrag[14], b2, a3, 0, 0, 0);
      a0 = __builtin_amdgcn_mfma_f32_16x16x32_bf16(afrag[3],  b3, a0, 0, 0, 0);
      a1 = __builtin_amdgcn_mfma_f32_16x16x32_bf16(afrag[7],  b3, a1, 0, 0, 0);
      a2 = __builtin_amdgcn_mfma_f32_16x16x32_bf16(afrag[11], b3, a2, 0, 0, 0);
      a3 = __builtin_amdgcn_mfma_f32_16x16x32_bf16(afrag[15], b3, a3, 0, 0, 0);
      const unsigned int rowc = (unsigned int)row;
      #pragma unroll
      for (int r = 0; r < 4; ++r) {
        unsigned int k0 = (__float_as_uint(a0[r]) & 0xFFFFFC00u) | rowc;
        if (k0 < kmin[r]) kmin[r] = k0;
        unsigned int k1 = (__float_as_uint(a1[r]) & 0xFFFFFC00u) | rowc;
        if (k1 < kmin[4 + r]) kmin[4 + r] = k1;
        unsigned int k2 = (__float_as_uint(a2[r]) & 0xFFFFFC00u) | rowc;
        if (k2 < kmin[8 + r]) kmin[8 + r] = k2;
        unsigned int k3 = (__float_as_uint(a3[r]) & 0xFFFFFC00u) | rowc;
        if (k3 < kmin[12 + r]) kmin[12 + r] = k3;
      }
    }
    if (ch < 15) {
      #pragma unroll
      for (int p = 0; p < 4; ++p) bG[cur ^ 1][p * 256 + t] = st[p];
    }
    __syncthreads();   // next-chunk writes visible; cur free for re-stage
  }

  // ---- in-wave butterfly u32-min over the 16 code-lanes of each quad
  #pragma unroll
  for (int m = 1; m <= 8; m <<= 1) {
    #pragma unroll
    for (int i = 0; i < 16; ++i) {
      unsigned int o = (unsigned int)__shfl_xor((int)kmin[i], m, 64);
      if (o < kmin[i]) kmin[i] = o;
    }
  }
  if (nL == 0) {
    #pragma unroll
    for (int mt = 0; mt < 4; ++mt)
      #pragma unroll
      for (int r = 0; r < 4; ++r)
        mergeK[ph * 64 + mt * 16 + q * 4 + r][kh] = kmin[mt * 4 + r];
  }
  __syncthreads();

  // ---- cross-half merge (2-way u32 min per pixel)
  if (t < 128) {
    unsigned int b = min(mergeK[t][0], mergeK[t][1]);
    int bi = (int)(b & 1023u);
    widx[t] = bi;
    used[bi] = 1;   // benign same-value race; kernel boundary = coherence
  }
  __syncthreads();

  // ---- epilogue: e from raw bf16 rows, z from zG (no global z re-read)
  float lsum = 0.f;
  {
    const int p = t & 127, cg = t >> 7;    // 2 channel halves x 64 ch
    const int idx = widx[p];
    const int pt = p >> 4, mL = p & 15;
    const int obase = zoff + p;
    #pragma unroll 2
    for (int j8 = 0; j8 < 8; ++j8) {
      const int ks = cg * 2 + (j8 >> 2), qq = j8 & 3;
      uint4 eg = ebv[idx * 16 + ks * 4 + qq];
      uint4 zg = zG[ks * 512 + pt * 64 + qq * 16 + ((mL + 4 * (pt + qq)) & 15)];
      const unsigned int ew[4] = {eg.x, eg.y, eg.z, eg.w};
      const unsigned int zw[4] = {zg.x, zg.y, zg.z, zg.w};
      #pragma unroll
      for (int hw = 0; hw < 4; ++hw) {
        float e0 = __uint_as_float(ew[hw] << 16);
        float e1 = __uint_as_float(ew[hw] & 0xFFFF0000u);
        float z0 = -0.5f * __uint_as_float(zw[hw] << 16);
        float z1 = -0.5f * __uint_as_float(zw[hw] & 0xFFFF0000u);
        int off = obase + (ks * 32 + qq * 8 + hw * 2) * 4096;
        out[off] = e0;                     // lanes over p -> 256B contiguous
        float d0 = z0 - e0; lsum += d0 * d0;
        out[off + 4096] = e1;
        float d1 = z1 - e1; lsum += d1 * d1;
      }
    }
  }
  #pragma unroll
  for (int o = 32; o > 0; o >>= 1) lsum += __shfl_down(lsum, o, 64);
  if (L == 0) wsum[wv] = lsum;
  __syncthreads();
  if (t == 0) lossp[blockIdx.x] = wsum[0] + wsum[1] + wsum[2] + wsum[3];
}

// ---- F: usage count + loss finalize ----
__global__ void finalize_kernel(const int* __restrict__ used,
                                const float* __restrict__ lossp,
                                float* __restrict__ out2) {
  __shared__ int   redi[256];
  __shared__ float redf[256];
  int t = threadIdx.x;
  int s = 0;
  for (int i = t; i < K_CODES; i += 256) s += (used[i] != 0) ? 1 : 0;
  float ls = 0.f;
  for (int i = t; i < NBLK; i += 256) ls += lossp[i];
  redi[t] = s; redf[t] = ls;
  __syncthreads();
  for (int o = 128; o > 0; o >>= 1) {
    if (t < o) { redi[t] += redi[t + o]; redf[t] += redf[t + o]; }
    __syncthreads();
  }
  if (t == 0) {
    out2[0] = 1.25f * redf[0] / (float)TOT;  // (1+0.25)*MSE
    out2[1] = (float)redi[0] / 1024.0f;
  }
}

extern "C" void kernel_launch(void* const* d_in, const int* in_sizes, int n_in,
                              void* d_out, int out_size, void* d_ws, size_t ws_size,
                              hipStream_t stream) {
  const float* z  = (const float*)d_in[0];
  const float* cb = (const float*)d_in[1];
  float* out = (float*)d_out;
  char* ws = (char*)d_ws;
  unsigned short* ebf  = (unsigned short*)ws;         // 262144 B raw bf16 rows
  unsigned short* ebsw = (unsigned short*)(ws + 262144); // 262144 B swizzled
  float* nsq1  = (float*)(ws + 524288);               // 4096 B
  int*   used  = (int*)(ws + 528384);                 // 4096 B
  float* lossp = (float*)(ws + 532480);               // 2048 B per-block partials

  hipLaunchKernelGGL(prep_kernel, dim3(512), dim3(256), 0, stream,
                     cb, ebf, ebsw, nsq1, used);
  hipLaunchKernelGGL(vq_main, dim3(NBLK), dim3(256), 0, stream,
                     z, ebf, ebsw, nsq1, used, lossp, out);
  hipLaunchKernelGGL(finalize_kernel, dim3(1), dim3(256), 0, stream,
                     used, lossp, out + TOT);
}